// Round 2
// baseline (980.464 us; speedup 1.0000x reference)
//
#include <hip/hip_runtime.h>
#include <cstdint>
#include <cstddef>

typedef __attribute__((ext_vector_type(8))) short bf16x8;   // 8 bf16 = 4 VGPRs
typedef __attribute__((ext_vector_type(4))) float floatx4;  // MFMA C/D frag

#define NBATCH 16
#define CIN    512
#define COUT   512
#define HH     64
#define WW     64
#define HP     66                 // padded H/W (+1 halo each side)
#define XSLOT  72                 // c-slot per (row,col): 64 data + 8 pad bf16 (144 B) -> conflict-free b128
#define XSZ    (4 * 66 * XSLOT)   // 19008 ushorts = 38016 B: X patch 4 rows x 66 cols x 64 c

static __device__ __forceinline__ unsigned short f2bf(float f) {
  union { float f; unsigned u; } cv; cv.f = f;
  unsigned u = cv.u;
  return (unsigned short)((u + 0x7FFFu + ((u >> 16) & 1u)) >> 16);  // RNE
}

// K0: zero only the halo border of xmp (d_ws is re-poisoned 0xAA before every call)
__global__ void k_halo(unsigned short* __restrict__ xmp) {
  int idx = blockIdx.x * 256 + threadIdx.x;
  if (idx >= NBATCH * 260 * 64) return;
  int ch   = idx & 63;
  int cell = (idx >> 6) % 260;
  int n    = (idx >> 6) / 260;
  int h, w;
  if      (cell < 66)  { h = 0;              w = cell;       }
  else if (cell < 132) { h = 65;             w = cell - 66;  }
  else if (cell < 196) { h = cell - 132 + 1; w = 0;          }
  else                 { h = cell - 196 + 1; w = 65;         }
  uint4 z = {0u, 0u, 0u, 0u};
  *(uint4*)(xmp + (((size_t)n * HP + h) * HP + w) * CIN + ch * 8) = z;
}

// K1: w2t[c][o] = sum_r w[o][c][r]^2 ; wr[r][o][c] = bf16(w[o][c][r])
__global__ void k_wprep(const float* __restrict__ w, unsigned short* __restrict__ wr,
                        float* __restrict__ w2t) {
  int o = blockIdx.x;
  int c = blockIdx.y * 256 + threadIdx.x;
  const float* wp = w + ((size_t)o * CIN + c) * 9;
  float v[9]; float sum = 0.f;
#pragma unroll
  for (int r = 0; r < 9; ++r) { v[r] = wp[r]; sum += v[r] * v[r]; }
  w2t[(size_t)c * COUT + o] = sum;
#pragma unroll
  for (int r = 0; r < 9; ++r)
    wr[((size_t)r * COUT + o) * CIN + c] = f2bf(v[r]);
}

// K2: d[n][o] = rsqrt(sum_c s[n][c]^2 * w2t[c][o] + 1e-8)  (fp32 exact path)
// grid (COUT/64, NBATCH), 256 thr = 64 o x 4 c-groups; LDS reduce over groups.
__global__ void k_dcoef(const float* __restrict__ s, const float* __restrict__ w2t,
                        float* __restrict__ d) {
  __shared__ float s2[CIN];
  __shared__ float partial[4][64];
  int n  = blockIdx.y;
  int ol = threadIdx.x & 63;
  int cg = threadIdx.x >> 6;
  int o  = blockIdx.x * 64 + ol;
  for (int c = threadIdx.x; c < CIN; c += 256) {
    float sv = s[n * CIN + c]; s2[c] = sv * sv;
  }
  __syncthreads();
  float sum = 0.f;
#pragma unroll 8
  for (int i = 0; i < 128; ++i) {
    int c = cg * 128 + i;
    sum += s2[c] * w2t[(size_t)c * COUT + o];   // lanes coalesced along o
  }
  partial[cg][ol] = sum;
  __syncthreads();
  if (cg == 0) {
    float t = partial[0][ol] + partial[1][ol] + partial[2][ol] + partial[3][ol];
    d[n * COUT + o] = rsqrtf(t + 1e-8f);
  }
}

// K3: xmp[n][h+1][w+1][c] = bf16(x[n][c][h][w] * s[n][c]); NHWC padded
__global__ void k_xmod(const float* __restrict__ x, const float* __restrict__ s,
                       unsigned short* __restrict__ xmp) {
  __shared__ __align__(16) unsigned short tile[WW * 520];   // [w][c], row stride 520
  int tid  = threadIdx.x;
  int n    = blockIdx.x >> 6;
  int h    = blockIdx.x & 63;
  int wcol = tid & 63;
  int grp  = tid >> 6;
#pragma unroll
  for (int i = 0; i < 16; ++i) {
    int c0 = (i * 4 + grp) * 8;
    bf16x8 pk;
#pragma unroll
    for (int j = 0; j < 8; ++j) {
      int c = c0 + j;
      float v = x[(((size_t)n * CIN + c) * HH + h) * WW + wcol] * s[n * CIN + c];
      pk[j] = (short)f2bf(v);
    }
    *(bf16x8*)(tile + wcol * 520 + c0) = pk;
  }
  __syncthreads();
#pragma unroll
  for (int i = 0; i < 16; ++i) {
    int wv = i * 4 + grp;
    bf16x8 v = *(const bf16x8*)(tile + wv * 520 + wcol * 8);
    *(bf16x8*)(xmp + (((size_t)n * HP + (h + 1)) * HP + (wv + 1)) * CIN + wcol * 8) = v;
  }
}

// Main: shift-GEMM. Block = 256 thr (4 waves), tile 128 Cout x 128 pixels (2 rows x 64 w).
// X patch in LDS (padded, conflict-free); W A-fragments loaded per-lane DIRECTLY from
// global (L2-resident, K-contiguous) -> no As buffer, no inner barriers (2 per cb only).
// MFMA 16x16x32_bf16: A[m=lane&15][k=quad*8+j], B[k=quad*8+j][n=lane&15], D[m=quad*4+i][n=lane&15].
__global__ __launch_bounds__(256, 3)
void k_conv(const unsigned short* __restrict__ xmp, const unsigned short* __restrict__ wr,
            const float* __restrict__ d, const float* __restrict__ bias,
            const float* __restrict__ noise, float* __restrict__ out) {
  __shared__ __align__(16) unsigned short Xs[XSZ];          // 38016 B

  int tid  = threadIdx.x;
  int lane = tid & 63;
  int l15  = lane & 15;
  int quad = lane >> 4;
  int wv   = tid >> 6;
  int wrow = wv & 1;    // which of the 2 pixel rows this wave owns
  int woc  = wv >> 1;   // which 64-wide Cout half

  int bx  = blockIdx.x;
  int n   = bx >> 5;
  int h0  = (bx & 31) * 2;
  int ocb = blockIdx.y * 128;

  // per-lane W base: A-frag row o = ocb + woc*64 + mf*16 + l15, k-offset quad*8
  const unsigned short* wrl = wr + ((size_t)(ocb + woc * 64 + l15)) * CIN + quad * 8;

  floatx4 acc[4][4];
#pragma unroll
  for (int a = 0; a < 4; ++a)
#pragma unroll
    for (int b = 0; b < 4; ++b)
#pragma unroll
      for (int q = 0; q < 4; ++q) acc[a][b][q] = 0.f;

  for (int cb = 0; cb < 8; ++cb) {
    int c0 = cb * 64;
    // ---- load X patch chunks into registers BEFORE the barrier (no LDS dependency)
    bf16x8 xv[8], xt;
#pragma unroll
    for (int i = 0; i < 8; ++i) {
      int idx = i * 256 + tid;
      int row = idx / 528;                   // 528 = 66 cols * 8 c-chunks
      int rem = idx - row * 528;
      int col = rem >> 3, ch = rem & 7;
      xv[i] = *(const bf16x8*)(xmp + (((size_t)n * HP + (h0 + row)) * HP + col) * CIN + c0 + ch * 8);
    }
    if (tid < 64) {                          // tail chunks 2048..2111
      int rem = 464 + tid;
      int col = rem >> 3, ch = rem & 7;
      xt = *(const bf16x8*)(xmp + (((size_t)n * HP + (h0 + 3)) * HP + col) * CIN + c0 + ch * 8);
    }
    __syncthreads();                         // all waves done reading previous Xs
#pragma unroll
    for (int i = 0; i < 8; ++i) {
      int idx = i * 256 + tid;
      int row = idx / 528;
      int rem = idx - row * 528;
      int col = rem >> 3, ch = rem & 7;
      *(bf16x8*)(Xs + (row * 66 + col) * XSLOT + ch * 8) = xv[i];
    }
    if (tid < 64) {
      int rem = 464 + tid;
      int col = rem >> 3, ch = rem & 7;
      *(bf16x8*)(Xs + (3 * 66 + col) * XSLOT + ch * 8) = xt;
    }
    __syncthreads();

#pragma unroll
    for (int r = 0; r < 9; ++r) {
      int kh = r / 3;
      int kw = r - kh * 3;
      int xrow = wrow + kh;
      bf16x8 af[2][4], bfv[2][4];
#pragma unroll
      for (int ks = 0; ks < 2; ++ks)
#pragma unroll
        for (int mf = 0; mf < 4; ++mf)
          af[ks][mf] = *(const bf16x8*)(wrl + ((size_t)r * COUT + mf * 16) * CIN + c0 + ks * 32);
#pragma unroll
      for (int ks = 0; ks < 2; ++ks)
#pragma unroll
        for (int nf = 0; nf < 4; ++nf)
          bfv[ks][nf] = *(const bf16x8*)(Xs + (xrow * 66 + (nf * 16 + l15 + kw)) * XSLOT + ks * 32 + quad * 8);
#pragma unroll
      for (int ks = 0; ks < 2; ++ks)
#pragma unroll
        for (int mf = 0; mf < 4; ++mf)
#pragma unroll
          for (int nf = 0; nf < 4; ++nf)
            acc[mf][nf] = __builtin_amdgcn_mfma_f32_16x16x32_bf16(af[ks][mf], bfv[ks][nf], acc[mf][nf], 0, 0, 0);
    }
  }

  // ---- fused epilogue: out = leakyrelu(acc * d[n,o] + b[o] + noise)
  int h = h0 + wrow;
#pragma unroll
  for (int mf = 0; mf < 4; ++mf) {
#pragma unroll
    for (int i = 0; i < 4; ++i) {
      int o = ocb + woc * 64 + mf * 16 + quad * 4 + i;
      float dd = d[n * COUT + o];
      float bb = bias[o];
      size_t base = (((size_t)n * COUT + o) * HH + h) * WW;
#pragma unroll
      for (int nf = 0; nf < 4; ++nf) {
        int wc = nf * 16 + l15;        // lanes contiguous along w -> coalesced
        float v = acc[mf][nf][i] * dd + bb + noise[base + wc];
        out[base + wc] = (v >= 0.f) ? v : 0.2f * v;
      }
    }
  }
}

extern "C" void kernel_launch(void* const* d_in, const int* in_sizes, int n_in,
                              void* d_out, int out_size, void* d_ws, size_t ws_size,
                              hipStream_t stream) {
  (void)in_sizes; (void)n_in; (void)out_size; (void)ws_size;
  const float* x     = (const float*)d_in[0];
  const float* s     = (const float*)d_in[1];
  const float* noise = (const float*)d_in[2];
  const float* w     = (const float*)d_in[3];
  const float* bias  = (const float*)d_in[4];
  float* out = (float*)d_out;

  char* ws = (char*)d_ws;
  const size_t XMP_BYTES = (size_t)NBATCH * HP * HP * CIN * 2;  // 71,368,704
  const size_t WR_BYTES  = (size_t)9 * COUT * CIN * 2;          //  4,718,592
  const size_t W2_BYTES  = (size_t)CIN * COUT * 4;              //  1,048,576
  unsigned short* xmp = (unsigned short*)ws;
  unsigned short* wrr = (unsigned short*)(ws + XMP_BYTES);
  float* w2t          = (float*)(ws + XMP_BYTES + WR_BYTES);
  float* dcoef        = (float*)(ws + XMP_BYTES + WR_BYTES + W2_BYTES);

  k_halo <<<dim3((NBATCH * 260 * 64 + 255) / 256), 256, 0, stream>>>(xmp);
  k_wprep<<<dim3(COUT, 2),  256, 0, stream>>>(w, wrr, w2t);
  k_dcoef<<<dim3(COUT / 64, NBATCH), 256, 0, stream>>>(s, w2t, dcoef);
  k_xmod <<<dim3(NBATCH * HH), 256, 0, stream>>>(x, s, xmp);
  k_conv <<<dim3(NBATCH * HH / 2, COUT / 128), 256, 0, stream>>>(xmp, wrr, dcoef, bias, noise, out);
}